// Round 11
// baseline (389.495 us; speedup 1.0000x reference)
//
#include <hip/hip_runtime.h>
#include <hip/hip_bf16.h>
#include <cstring>

// GAT 2-layer forward, MI355X (gfx950). All float tensors F32 (resolved R9).
// R11 = R10 green (347 us) with ONE concept changed: both GEMMs restructured
// from node-owning threads (4 ds_read + 1 scalar W load per 4 FMA; LDS-bound)
// to channel-owning threads (1 float4 W load + 1-2 broadcast ds_read per 4-8
// FMA; FMA-bound). Att-dot epilogue gets rotated c2 start to break the 32-way
// LDS bank conflict (was 600K conflicts/dispatch). 16-node tiles (50000%16==0).
// Aggregation kernels, CSR build, workspace: byte-identical to R10.

#define HEADS 4
#define HID   32
#define F1    128
#define F2    64
#define NEG   0.2f
#define SCHUNK 512

typedef __hip_bfloat16 bf16;
__device__ __forceinline__ float b2f(bf16 v) { return __bfloat162float(v); }
__device__ __forceinline__ float lrelu(float v) { return v > 0.f ? v : NEG * v; }
__device__ __forceinline__ float lo16(unsigned u) { return __uint_as_float(u << 16); }
__device__ __forceinline__ float hi16(unsigned u) { return __uint_as_float(u & 0xFFFF0000u); }

// ---------------- CSR build ----------------
__global__ void k_deg(const int* __restrict__ dst, int E, int* __restrict__ deg) {
    int i = blockIdx.x * blockDim.x + threadIdx.x;
    if (i < E) atomicAdd(&deg[dst[i]], 1);
}

__global__ void k_scan1(const int* __restrict__ deg, int N,
                        int* __restrict__ rowp, int* __restrict__ bsum) {
    __shared__ int s[SCHUNK];
    int t = threadIdx.x;
    int i = blockIdx.x * SCHUNK + t;
    int v = (i < N) ? deg[i] : 0;
    s[t] = v;
    __syncthreads();
    for (int off = 1; off < SCHUNK; off <<= 1) {
        int add = (t >= off) ? s[t - off] : 0;
        __syncthreads();
        s[t] += add;
        __syncthreads();
    }
    if (i < N) rowp[i] = s[t] - v;
    if (t == SCHUNK - 1) bsum[blockIdx.x] = s[t];
}

__global__ void k_scan2(int* __restrict__ bsum, int nb, int* __restrict__ rowp, int N) {
    if (blockIdx.x == 0 && threadIdx.x == 0) {
        int run = 0;
        for (int b = 0; b < nb; b++) { int t = bsum[b]; bsum[b] = run; run += t; }
        rowp[N] = run;
    }
}

__global__ void k_scan3(int* __restrict__ rowp, const int* __restrict__ bsum,
                        int N, int* __restrict__ cursor) {
    int i = blockIdx.x * SCHUNK + threadIdx.x;
    if (i < N) {
        int r = rowp[i] + bsum[blockIdx.x];
        rowp[i] = r;
        cursor[i] = r;
    }
}

__global__ void k_scatter(const int* __restrict__ src, const int* __restrict__ dst,
                          int E, int* __restrict__ cursor, int* __restrict__ csr) {
    int i = blockIdx.x * blockDim.x + threadIdx.x;
    if (i < E) {
        int p = atomicAdd(&cursor[dst[i]], 1);
        csr[p] = src[i];
    }
}

__global__ void k_wsfail(unsigned* out_u, long nwords, unsigned w) {
    long i = blockIdx.x * (long)blockDim.x + threadIdx.x;
    if (i < nwords) out_u[i] = w;
}

// ------- Layer 1 GEMM: 16 nodes/block, channel-owning threads -------
__global__ __launch_bounds__(256) void
k_gemm1(const float* __restrict__ x, const float* __restrict__ W,
        const float* __restrict__ atts, const float* __restrict__ attd,
        int N, bf16* __restrict__ h1,
        float* __restrict__ as1, float* __restrict__ ad1) {
    __shared__ float xs[16 * F1];   // 8 KB
    __shared__ float hs[16 * F1];   // 8 KB
    int t = threadIdx.x;
    int nb = blockIdx.x * 16;
    {   // stage 16 x-rows, float4-coalesced (512 float4)
        const float4* xv = (const float4*)(x + (size_t)nb * F1);
        float4* sv = (float4*)xs;
        for (int i = t; i < 512; i += 256) {
            int n = nb + (i >> 5);
            sv[i] = (n < N) ? xv[i] : make_float4(0.f, 0.f, 0.f, 0.f);
        }
    }
    __syncthreads();
    int cg = t & 31;          // channels 4cg..4cg+3
    int np = t >> 5;          // nodes np, np+8
    float a0[4] = {0.f, 0.f, 0.f, 0.f};
    float a1[4] = {0.f, 0.f, 0.f, 0.f};
    const float* wp = W + cg * 4;
    for (int k = 0; k < F1; k++) {
        float4 w = *(const float4*)(wp + (size_t)k * F1);
        float xa = xs[np * F1 + k];          // 2 addrs/wave -> free broadcast
        float xb = xs[(np + 8) * F1 + k];
        a0[0] += xa * w.x; a0[1] += xa * w.y; a0[2] += xa * w.z; a0[3] += xa * w.w;
        a1[0] += xb * w.x; a1[1] += xb * w.y; a1[2] += xb * w.z; a1[3] += xb * w.w;
    }
    int n0 = nb + np, n1 = nb + np + 8;
    #pragma unroll
    for (int j = 0; j < 4; j++) {
        hs[np * F1 + cg * 4 + j] = a0[j];
        hs[(np + 8) * F1 + cg * 4 + j] = a1[j];
        if (n0 < N) h1[(size_t)n0 * F1 + cg * 4 + j] = __float2bfloat16(a0[j]);
        if (n1 < N) h1[(size_t)n1 * F1 + cg * 4 + j] = __float2bfloat16(a1[j]);
    }
    __syncthreads();
    if (t < 128) {  // 16 nodes * 4 heads * {src,dst}
        int loc = t >> 3, head = (t >> 1) & 3, isd = t & 1;
        const float* av = isd ? attd : atts;
        float s = 0.f;
        int rot = t & 31;
        for (int i = 0; i < HID; i++) {
            int c2 = (i + rot) & (HID - 1);  // rotated start: banks spread
            s += hs[loc * F1 + head * HID + c2] * av[head * HID + c2];
        }
        int n = nb + loc;
        if (n < N) (isd ? ad1 : as1)[n * HEADS + head] = s;
    }
}

// ------- Layer 1 aggregate: wave=node, 4 edge slots, single pass (R10) -------
__global__ void k_agg1(const bf16* __restrict__ h1, const float* __restrict__ as1,
                       const float* __restrict__ ad1, const int* __restrict__ rowp,
                       const int* __restrict__ csr, const float* __restrict__ b1,
                       int N, float* __restrict__ feat) {
    int wave = threadIdx.x >> 6, lane = threadIdx.x & 63;
    int n = blockIdx.x * 4 + wave;
    if (n >= N) return;
    int r0 = rowp[n], r1 = rowp[n + 1];
    int sub = lane >> 4;
    int cl  = lane & 15;
    int head = cl >> 2;
    float adh = ad1[n * 4 + head];
    float acc[8] = {0.f, 0.f, 0.f, 0.f, 0.f, 0.f, 0.f, 0.f};
    float ssum = 0.f;
    for (int j0 = r0; j0 < r1; j0 += 4) {
        int j = j0 + sub;
        float p = 0.f;
        int sn = 0;
        if (j < r1) {
            sn = csr[j];
            p = __expf(lrelu(as1[(size_t)sn * 4 + head] + adh));
        }
        const uint4 hv = *(const uint4*)(h1 + (size_t)sn * F1 + cl * 8);
        acc[0] += p * lo16(hv.x);
        acc[1] += p * hi16(hv.x);
        acc[2] += p * lo16(hv.y);
        acc[3] += p * hi16(hv.y);
        acc[4] += p * lo16(hv.z);
        acc[5] += p * hi16(hv.z);
        acc[6] += p * lo16(hv.w);
        acc[7] += p * hi16(hv.w);
        ssum += p;
    }
    for (int off = 16; off < 64; off <<= 1) {
        ssum += __shfl_xor(ssum, off);
        #pragma unroll
        for (int k = 0; k < 8; k++) acc[k] += __shfl_xor(acc[k], off);
    }
    if (sub == 0) {
        float inv = 1.f / (ssum + 1e-16f);
        float* fp = feat + (size_t)n * F1 + cl * 8;
        #pragma unroll
        for (int k = 0; k < 8; k++) {
            float v = acc[k] * inv + b1[cl * 8 + k];
            fp[k] = v > 0.f ? v : 0.f;
        }
    }
}

// ------- Layer 2 GEMM: 16 nodes/block, channel-owning threads -------
__global__ __launch_bounds__(256) void
k_gemm2(const float* __restrict__ feat, const float* __restrict__ W,
        const float* __restrict__ atts, const float* __restrict__ attd,
        int N, bf16* __restrict__ h2,
        float* __restrict__ as2, float* __restrict__ ad2) {
    __shared__ float fs[16 * F1];   // 8 KB
    __shared__ float hs[16 * F2];   // 4 KB
    int t = threadIdx.x;
    int nb = blockIdx.x * 16;
    {
        const float4* fv = (const float4*)(feat + (size_t)nb * F1);
        float4* sv = (float4*)fs;
        for (int i = t; i < 512; i += 256) {
            int n = nb + (i >> 5);
            sv[i] = (n < N) ? fv[i] : make_float4(0.f, 0.f, 0.f, 0.f);
        }
    }
    __syncthreads();
    int cg = t & 15;   // channels 4cg..4cg+3 (of 64)
    int np = t >> 4;   // node np (0..15)
    float acc[4] = {0.f, 0.f, 0.f, 0.f};
    const float* wp = W + cg * 4;
    for (int k = 0; k < F1; k++) {
        float4 w = *(const float4*)(wp + (size_t)k * F2);
        float xa = fs[np * F1 + k];
        acc[0] += xa * w.x; acc[1] += xa * w.y; acc[2] += xa * w.z; acc[3] += xa * w.w;
    }
    int n0 = nb + np;
    #pragma unroll
    for (int j = 0; j < 4; j++) {
        hs[np * F2 + cg * 4 + j] = acc[j];
        if (n0 < N) h2[(size_t)n0 * F2 + cg * 4 + j] = __float2bfloat16(acc[j]);
    }
    __syncthreads();
    if (t < 32) {  // 16 nodes * {src,dst}
        int loc = t >> 1, isd = t & 1;
        const float* av = isd ? attd : atts;
        float s = 0.f;
        int rot = (t * 2) & (F2 - 1);
        for (int i = 0; i < F2; i++) {
            int c2 = (i + rot) & (F2 - 1);
            s += hs[loc * F2 + c2] * av[c2];
        }
        int n = nb + loc;
        if (n < N) (isd ? ad2 : as2)[n] = s;
    }
}

// ------- Layer 2 aggregate: wave=node, 4 edge slots, single pass (R10) -------
__global__ void k_agg2(const bf16* __restrict__ h2, const float* __restrict__ as2,
                       const float* __restrict__ ad2, const int* __restrict__ rowp,
                       const int* __restrict__ csr, const float* __restrict__ b2v,
                       int N, float* __restrict__ out) {
    int wave = threadIdx.x >> 6, lane = threadIdx.x & 63;
    int n = blockIdx.x * 4 + wave;
    if (n >= N) return;
    int r0 = rowp[n], r1 = rowp[n + 1];
    int sub = lane >> 4;
    int cl  = lane & 15;
    float ad = ad2[n];
    float acc[4] = {0.f, 0.f, 0.f, 0.f};
    float ssum = 0.f;
    for (int j0 = r0; j0 < r1; j0 += 4) {
        int j = j0 + sub;
        float p = 0.f;
        int sn = 0;
        if (j < r1) {
            sn = csr[j];
            p = __expf(lrelu(as2[sn] + ad));
        }
        const uint2 hv = *(const uint2*)(h2 + (size_t)sn * F2 + cl * 4);
        acc[0] += p * lo16(hv.x);
        acc[1] += p * hi16(hv.x);
        acc[2] += p * lo16(hv.y);
        acc[3] += p * hi16(hv.y);
        ssum += p;
    }
    for (int off = 16; off < 64; off <<= 1) {
        ssum += __shfl_xor(ssum, off);
        #pragma unroll
        for (int k = 0; k < 4; k++) acc[k] += __shfl_xor(acc[k], off);
    }
    if (sub == 0) {
        float inv = 1.f / (ssum + 1e-16f);
        float* op = out + (size_t)n * F2 + cl * 4;
        #pragma unroll
        for (int k = 0; k < 4; k++) op[k] = acc[k] * inv + b2v[cl * 4 + k];
    }
}

extern "C" void kernel_launch(void* const* d_in, const int* in_sizes, int n_in,
                              void* d_out, int out_size, void* d_ws, size_t ws_size,
                              hipStream_t stream) {
    const float* x    = (const float*)d_in[0];
    const int* esrc   = (const int*)d_in[1];
    const int* edst   = (const int*)d_in[2];
    const float* W1   = (const float*)d_in[3];
    const float* at1s = (const float*)d_in[4];
    const float* at1d = (const float*)d_in[5];
    const float* b1   = (const float*)d_in[6];
    const float* W2   = (const float*)d_in[7];
    const float* at2s = (const float*)d_in[8];
    const float* at2d = (const float*)d_in[9];
    const float* b2   = (const float*)d_in[10];
    const int N = in_sizes[0] / F1;
    const int E = in_sizes[1];

    size_t off = 0;
    auto A = [&](size_t b) { size_t o = off; off = (off + b + 255) & ~(size_t)255; return o; };
    char* base = (char*)d_ws;
    size_t o_as1  = A((size_t)4 * N * 4);
    size_t o_ad1  = A((size_t)4 * N * 4);
    size_t o_h1   = A((size_t)N * F1 * 4);   // slab f32-sized; bf16 uses half
    size_t o_feat = A((size_t)N * F1 * 4);
    size_t o_deg  = A((size_t)N * 4);        // cursor aliases deg
    size_t o_rowp = A((size_t)(N + 1) * 4);
    size_t o_csr  = A((size_t)E * 4);
    size_t o_bsum = A(1024);
    size_t NEED = off;

    if (ws_size < NEED) {
        long nwords = (long)out_size;
        float val = 200.f;
        unsigned fb; memcpy(&fb, &val, 4);
        k_wsfail<<<(int)((nwords + 255) / 256), 256, 0, stream>>>(
            (unsigned*)d_out, nwords, fb);
        return;
    }

    float* as1  = (float*)(base + o_as1);
    float* ad1  = (float*)(base + o_ad1);
    float* as2  = as1;   // dead after agg1
    float* ad2  = ad1;
    bf16* h1    = (bf16*)(base + o_h1);
    bf16* h2    = h1;    // dead after agg1
    float* feat = (float*)(base + o_feat);
    int* deg    = (int*)(base + o_deg);
    int* cursor = deg;   // dead after scan1
    int* rowp   = (int*)(base + o_rowp);
    int* csr    = (int*)(base + o_csr);
    int* bsum   = (int*)(base + o_bsum);

    hipMemsetAsync(deg, 0, (size_t)N * 4, stream);

    k_deg<<<(E + 255) / 256, 256, 0, stream>>>(edst, E, deg);
    int nblk = (N + SCHUNK - 1) / SCHUNK;
    k_scan1<<<nblk, SCHUNK, 0, stream>>>(deg, N, rowp, bsum);
    k_scan2<<<1, 64, 0, stream>>>(bsum, nblk, rowp, N);
    k_scan3<<<nblk, SCHUNK, 0, stream>>>(rowp, bsum, N, cursor);
    k_scatter<<<(E + 255) / 256, 256, 0, stream>>>(esrc, edst, E, cursor, csr);

    k_gemm1<<<(N + 15) / 16, 256, 0, stream>>>(x, W1, at1s, at1d, N, h1, as1, ad1);
    k_agg1<<<(N + 3) / 4, 256, 0, stream>>>(h1, as1, ad1, rowp, csr, b1, N, feat);

    k_gemm2<<<(N + 15) / 16, 256, 0, stream>>>(feat, W2, at2s, at2d, N, h2, as2, ad2);
    k_agg2<<<(N + 3) / 4, 256, 0, stream>>>(h2, as2, ad2, rowp, csr, b2, N, (float*)d_out);
}

// Round 12
// 317.039 us; speedup vs baseline: 1.2285x; 1.2285x over previous
//
#include <hip/hip_runtime.h>
#include <hip/hip_bf16.h>
#include <cstring>

// GAT 2-layer forward, MI355X (gfx950). All float tensors F32 (resolved R9).
// R12 = R10 green (347 us; R11's channel-owning GEMM regressed and is
// reverted) with ONE experimental delta: k_scatter (writeback-bound, VALU
// idle) and k_gemm1 (VALU/LDS-bound, HBM idle) fused into one kernel with
// Bresenham-interleaved block roles so both are co-resident and overlap
// their disjoint bottleneck pipes. Bodies byte-identical to R10's.

#define HEADS 4
#define HID   32
#define F1    128
#define F2    64
#define NEG   0.2f
#define SCHUNK 512

typedef __hip_bfloat16 bf16;
__device__ __forceinline__ float b2f(bf16 v) { return __bfloat162float(v); }
__device__ __forceinline__ float lrelu(float v) { return v > 0.f ? v : NEG * v; }
__device__ __forceinline__ float lo16(unsigned u) { return __uint_as_float(u << 16); }
__device__ __forceinline__ float hi16(unsigned u) { return __uint_as_float(u & 0xFFFF0000u); }

// ---------------- CSR build ----------------
__global__ void k_deg(const int* __restrict__ dst, int E, int* __restrict__ deg) {
    int i = blockIdx.x * blockDim.x + threadIdx.x;
    if (i < E) atomicAdd(&deg[dst[i]], 1);
}

__global__ void k_scan1(const int* __restrict__ deg, int N,
                        int* __restrict__ rowp, int* __restrict__ bsum) {
    __shared__ int s[SCHUNK];
    int t = threadIdx.x;
    int i = blockIdx.x * SCHUNK + t;
    int v = (i < N) ? deg[i] : 0;
    s[t] = v;
    __syncthreads();
    for (int off = 1; off < SCHUNK; off <<= 1) {
        int add = (t >= off) ? s[t - off] : 0;
        __syncthreads();
        s[t] += add;
        __syncthreads();
    }
    if (i < N) rowp[i] = s[t] - v;
    if (t == SCHUNK - 1) bsum[blockIdx.x] = s[t];
}

__global__ void k_scan2(int* __restrict__ bsum, int nb, int* __restrict__ rowp, int N) {
    if (blockIdx.x == 0 && threadIdx.x == 0) {
        int run = 0;
        for (int b = 0; b < nb; b++) { int t = bsum[b]; bsum[b] = run; run += t; }
        rowp[N] = run;
    }
}

__global__ void k_scan3(int* __restrict__ rowp, const int* __restrict__ bsum,
                        int N, int* __restrict__ cursor) {
    int i = blockIdx.x * SCHUNK + threadIdx.x;
    if (i < N) {
        int r = rowp[i] + bsum[blockIdx.x];
        rowp[i] = r;
        cursor[i] = r;
    }
}

__global__ void k_wsfail(unsigned* out_u, long nwords, unsigned w) {
    long i = blockIdx.x * (long)blockDim.x + threadIdx.x;
    if (i < nwords) out_u[i] = w;
}

// ------- FUSED: Layer 1 GEMM (R10 body) + CSR scatter (R10 body) -------
// Block roles interleaved by exact Bresenham split: of T total blocks,
// S are scatter (s = b*S/T increments) and G are gemm tiles (g = b - s).
__global__ void k_gemm1_scat(const float* __restrict__ x, const float* __restrict__ W,
                             const float* __restrict__ atts, const float* __restrict__ attd,
                             int N, bf16* __restrict__ h1,
                             float* __restrict__ as1, float* __restrict__ ad1,
                             const int* __restrict__ esrc, const int* __restrict__ edst,
                             int E, int* __restrict__ cursor, int* __restrict__ csr,
                             int S, int T) {
    __shared__ float xs[8][F1];
    __shared__ float hs[8][F1];
    int b = blockIdx.x;
    int s = (int)((long)b * S / T);
    int is_scat = ((long)(b + 1) * S / T) > (long)s;
    if (is_scat) {   // ---- scatter role (R10 k_scatter body) ----
        int i = s * 256 + threadIdx.x;
        if (i < E) {
            int p = atomicAdd(&cursor[edst[i]], 1);
            csr[p] = esrc[i];
        }
        return;
    }
    // ---- gemm role (R10 k_gemm1 body, nb from gemm-tile index) ----
    int t = threadIdx.x;
    int nb = (b - s) * 8;
    for (int i = t; i < 8 * F1; i += 256) {
        int loc = i >> 7, c = i & 127;
        int n = nb + loc;
        xs[loc][c] = (n < N) ? x[(size_t)n * F1 + c] : 0.f;
    }
    __syncthreads();
    int c = t & 127;
    int half = t >> 7;
    float acc0 = 0.f, acc1 = 0.f, acc2 = 0.f, acc3 = 0.f;
    for (int k = 0; k < F1; k++) {
        float w = W[(size_t)k * F1 + c];
        acc0 += xs[half + 0][k] * w;
        acc1 += xs[half + 2][k] * w;
        acc2 += xs[half + 4][k] * w;
        acc3 += xs[half + 6][k] * w;
    }
    float accs[4] = {acc0, acc1, acc2, acc3};
    for (int r = 0; r < 4; r++) {
        int loc = half + 2 * r;
        int n = nb + loc;
        hs[loc][c] = accs[r];
        if (n < N) h1[(size_t)n * F1 + c] = __float2bfloat16(accs[r]);
    }
    __syncthreads();
    if (t < 64) {
        int loc = t >> 3;
        int head = (t >> 1) & 3;
        int isd = t & 1;
        const float* av = isd ? attd : atts;
        float sdot = 0.f;
        for (int c2 = 0; c2 < HID; c2++)
            sdot += hs[loc][head * HID + c2] * av[head * HID + c2];
        int n = nb + loc;
        if (n < N) (isd ? ad1 : as1)[n * HEADS + head] = sdot;
    }
}

// ------- Layer 1 aggregate: wave=node, 4 edge slots, single pass (R10) -------
__global__ void k_agg1(const bf16* __restrict__ h1, const float* __restrict__ as1,
                       const float* __restrict__ ad1, const int* __restrict__ rowp,
                       const int* __restrict__ csr, const float* __restrict__ b1,
                       int N, float* __restrict__ feat) {
    int wave = threadIdx.x >> 6, lane = threadIdx.x & 63;
    int n = blockIdx.x * 4 + wave;
    if (n >= N) return;
    int r0 = rowp[n], r1 = rowp[n + 1];
    int sub = lane >> 4;
    int cl  = lane & 15;
    int head = cl >> 2;
    float adh = ad1[n * 4 + head];
    float acc[8] = {0.f, 0.f, 0.f, 0.f, 0.f, 0.f, 0.f, 0.f};
    float ssum = 0.f;
    for (int j0 = r0; j0 < r1; j0 += 4) {
        int j = j0 + sub;
        float p = 0.f;
        int sn = 0;
        if (j < r1) {
            sn = csr[j];
            p = __expf(lrelu(as1[(size_t)sn * 4 + head] + adh));
        }
        const uint4 hv = *(const uint4*)(h1 + (size_t)sn * F1 + cl * 8);
        acc[0] += p * lo16(hv.x);
        acc[1] += p * hi16(hv.x);
        acc[2] += p * lo16(hv.y);
        acc[3] += p * hi16(hv.y);
        acc[4] += p * lo16(hv.z);
        acc[5] += p * hi16(hv.z);
        acc[6] += p * lo16(hv.w);
        acc[7] += p * hi16(hv.w);
        ssum += p;
    }
    for (int off = 16; off < 64; off <<= 1) {
        ssum += __shfl_xor(ssum, off);
        #pragma unroll
        for (int k = 0; k < 8; k++) acc[k] += __shfl_xor(acc[k], off);
    }
    if (sub == 0) {
        float inv = 1.f / (ssum + 1e-16f);
        float* fp = feat + (size_t)n * F1 + cl * 8;
        #pragma unroll
        for (int k = 0; k < 8; k++) {
            float v = acc[k] * inv + b1[cl * 8 + k];
            fp[k] = v > 0.f ? v : 0.f;
        }
    }
}

// ---------------- Layer 2 GEMM (R10 version) ----------------
__global__ void k_gemm2(const float* __restrict__ feat, const float* __restrict__ W,
                        const float* __restrict__ atts, const float* __restrict__ attd,
                        int N, bf16* __restrict__ h2,
                        float* __restrict__ as2, float* __restrict__ ad2) {
    __shared__ float fs[8][F1];
    __shared__ float hs[8][F2];
    int t = threadIdx.x;
    int nb = blockIdx.x * 8;
    for (int i = t; i < 8 * F1; i += 256) {
        int loc = i >> 7, c = i & 127;
        int n = nb + loc;
        fs[loc][c] = (n < N) ? feat[(size_t)n * F1 + c] : 0.f;
    }
    __syncthreads();
    int c = t & 63, q = t >> 6;
    float a0 = 0.f, a1 = 0.f;
    for (int k = 0; k < F1; k++) {
        float w = W[(size_t)k * F2 + c];
        a0 += fs[q][k] * w;
        a1 += fs[q + 4][k] * w;
    }
    hs[q][c] = a0;
    hs[q + 4][c] = a1;
    int n0 = nb + q, n1 = nb + q + 4;
    if (n0 < N) h2[(size_t)n0 * F2 + c] = __float2bfloat16(a0);
    if (n1 < N) h2[(size_t)n1 * F2 + c] = __float2bfloat16(a1);
    __syncthreads();
    if (t < 16) {
        int loc = t >> 1, isd = t & 1;
        const float* av = isd ? attd : atts;
        float s = 0.f;
        for (int c2 = 0; c2 < F2; c2++) s += hs[loc][c2] * av[c2];
        int n = nb + loc;
        if (n < N) (isd ? ad2 : as2)[n] = s;
    }
}

// ------- Layer 2 aggregate: wave=node, 4 edge slots, single pass (R10) -------
__global__ void k_agg2(const bf16* __restrict__ h2, const float* __restrict__ as2,
                       const float* __restrict__ ad2, const int* __restrict__ rowp,
                       const int* __restrict__ csr, const float* __restrict__ b2v,
                       int N, float* __restrict__ out) {
    int wave = threadIdx.x >> 6, lane = threadIdx.x & 63;
    int n = blockIdx.x * 4 + wave;
    if (n >= N) return;
    int r0 = rowp[n], r1 = rowp[n + 1];
    int sub = lane >> 4;
    int cl  = lane & 15;
    float ad = ad2[n];
    float acc[4] = {0.f, 0.f, 0.f, 0.f};
    float ssum = 0.f;
    for (int j0 = r0; j0 < r1; j0 += 4) {
        int j = j0 + sub;
        float p = 0.f;
        int sn = 0;
        if (j < r1) {
            sn = csr[j];
            p = __expf(lrelu(as2[sn] + ad));
        }
        const uint2 hv = *(const uint2*)(h2 + (size_t)sn * F2 + cl * 4);
        acc[0] += p * lo16(hv.x);
        acc[1] += p * hi16(hv.x);
        acc[2] += p * lo16(hv.y);
        acc[3] += p * hi16(hv.y);
        ssum += p;
    }
    for (int off = 16; off < 64; off <<= 1) {
        ssum += __shfl_xor(ssum, off);
        #pragma unroll
        for (int k = 0; k < 4; k++) acc[k] += __shfl_xor(acc[k], off);
    }
    if (sub == 0) {
        float inv = 1.f / (ssum + 1e-16f);
        float* op = out + (size_t)n * F2 + cl * 4;
        #pragma unroll
        for (int k = 0; k < 4; k++) op[k] = acc[k] * inv + b2v[cl * 4 + k];
    }
}

extern "C" void kernel_launch(void* const* d_in, const int* in_sizes, int n_in,
                              void* d_out, int out_size, void* d_ws, size_t ws_size,
                              hipStream_t stream) {
    const float* x    = (const float*)d_in[0];
    const int* esrc   = (const int*)d_in[1];
    const int* edst   = (const int*)d_in[2];
    const float* W1   = (const float*)d_in[3];
    const float* at1s = (const float*)d_in[4];
    const float* at1d = (const float*)d_in[5];
    const float* b1   = (const float*)d_in[6];
    const float* W2   = (const float*)d_in[7];
    const float* at2s = (const float*)d_in[8];
    const float* at2d = (const float*)d_in[9];
    const float* b2   = (const float*)d_in[10];
    const int N = in_sizes[0] / F1;
    const int E = in_sizes[1];

    size_t off = 0;
    auto A = [&](size_t b) { size_t o = off; off = (off + b + 255) & ~(size_t)255; return o; };
    char* base = (char*)d_ws;
    size_t o_as1  = A((size_t)4 * N * 4);
    size_t o_ad1  = A((size_t)4 * N * 4);
    size_t o_h1   = A((size_t)N * F1 * 4);   // slab f32-sized; bf16 uses half
    size_t o_feat = A((size_t)N * F1 * 4);
    size_t o_deg  = A((size_t)N * 4);        // cursor aliases deg
    size_t o_rowp = A((size_t)(N + 1) * 4);
    size_t o_csr  = A((size_t)E * 4);
    size_t o_bsum = A(1024);
    size_t NEED = off;

    if (ws_size < NEED) {
        long nwords = (long)out_size;
        float val = 200.f;
        unsigned fb; memcpy(&fb, &val, 4);
        k_wsfail<<<(int)((nwords + 255) / 256), 256, 0, stream>>>(
            (unsigned*)d_out, nwords, fb);
        return;
    }

    float* as1  = (float*)(base + o_as1);
    float* ad1  = (float*)(base + o_ad1);
    float* as2  = as1;   // dead after agg1
    float* ad2  = ad1;
    bf16* h1    = (bf16*)(base + o_h1);
    bf16* h2    = h1;    // dead after agg1
    float* feat = (float*)(base + o_feat);
    int* deg    = (int*)(base + o_deg);
    int* cursor = deg;   // dead after scan1
    int* rowp   = (int*)(base + o_rowp);
    int* csr    = (int*)(base + o_csr);
    int* bsum   = (int*)(base + o_bsum);

    hipMemsetAsync(deg, 0, (size_t)N * 4, stream);

    k_deg<<<(E + 255) / 256, 256, 0, stream>>>(edst, E, deg);
    int nblk = (N + SCHUNK - 1) / SCHUNK;
    k_scan1<<<nblk, SCHUNK, 0, stream>>>(deg, N, rowp, bsum);
    k_scan2<<<1, 64, 0, stream>>>(bsum, nblk, rowp, N);
    k_scan3<<<nblk, SCHUNK, 0, stream>>>(rowp, bsum, N, cursor);

    // fused gemm1 + scatter (Bresenham-interleaved block roles)
    int G = (N + 7) / 8;
    int S = (E + 255) / 256;
    int T = G + S;
    k_gemm1_scat<<<T, 256, 0, stream>>>(x, W1, at1s, at1d, N, h1, as1, ad1,
                                        esrc, edst, E, cursor, csr, S, T);

    k_agg1<<<(N + 3) / 4, 256, 0, stream>>>(h1, as1, ad1, rowp, csr, b1, N, feat);

    k_gemm2<<<(N + 7) / 8, 256, 0, stream>>>(feat, W2, at2s, at2d, N, h2, as2, ad2);
    k_agg2<<<(N + 3) / 4, 256, 0, stream>>>(h2, as2, ad2, rowp, csr, b2, N, (float*)d_out);
}